// Round 1
// baseline (845.631 us; speedup 1.0000x reference)
//
#include <hip/hip_runtime.h>
#include <hip/hip_bf16.h>
#include <math.h>

typedef __attribute__((ext_vector_type(8))) short bf16x8;
typedef __attribute__((ext_vector_type(4))) float f32x4;

#define B_    4
#define C_    512
#define HW_   84
#define HP_   86      // conv output spatial (84 + 2*2 - 3 + 1)
#define XP_   88      // zero-padded input spatial
#define NPIX  (HP_*HP_)   // 7396
#define XPIX  (XP_*XP_)   // 7744

struct Taps { float fu[12]; float fd[12]; };

// ---------- device helpers ----------
__device__ __forceinline__ unsigned short f2bf(float f) {
    unsigned int u = __float_as_uint(f);
    unsigned int r = (u + 0x7fffu + ((u >> 16) & 1u)) >> 16;   // RNE
    return (unsigned short)r;
}

// ---------- kernel 1: s = wlat @ (aff_w*g)^T + aff_b ; sn = s * rsqrt(mean(s^2)) ----------
__global__ __launch_bounds__(1024) void k_affine(const float* __restrict__ wlat,
                                                 const float* __restrict__ aff_w,
                                                 const float* __restrict__ aff_b,
                                                 float* __restrict__ sn) {
    __shared__ float wl[B_ * C_];
    __shared__ float red[1024];
    int tid = threadIdx.x;
    for (int i = tid; i < B_ * C_; i += 1024) wl[i] = wlat[i];
    __syncthreads();
    const float AFFG = 0.04419417382415922f;  // 1/sqrt(512)
    float sval[2]; float ssum = 0.f;
    #pragma unroll
    for (int r = 0; r < 2; r++) {
        int idx = tid + r * 1024; int b = idx >> 9; int cc = idx & 511;
        const float4* aw = (const float4*)(aff_w + (size_t)cc * 512);
        const float4* wv = (const float4*)(wl + b * 512);
        float acc = 0.f;
        for (int q = 0; q < 128; q++) {
            float4 a = aw[q]; float4 w = wv[q];
            acc += a.x * w.x + a.y * w.y + a.z * w.z + a.w * w.w;
        }
        float s = acc * AFFG + aff_b[cc];
        sval[r] = s; ssum += s * s;
    }
    red[tid] = ssum; __syncthreads();
    for (int off = 512; off > 0; off >>= 1) {
        if (tid < off) red[tid] += red[tid + off];
        __syncthreads();
    }
    float inv = rsqrtf(red[0] / 2048.f);
    #pragma unroll
    for (int r = 0; r < 2; r++) { int idx = tid + r * 1024; sn[idx] = sval[r] * inv; }
}

// ---------- kernel 2: weight norm; wn bf16 repack [kk][o][c]; w2[o][c] ----------
__global__ __launch_bounds__(256) void k_wprep(const float* __restrict__ conv_w,
                                               unsigned short* __restrict__ wn,
                                               float* __restrict__ w2) {
    int o = blockIdx.x; int tid = threadIdx.x;
    const float* wo = conv_w + (size_t)o * 4608;
    __shared__ float red[256];
    float ss = 0.f;
    for (int i = tid; i < 4608; i += 256) { float v = wo[i]; ss += v * v; }
    red[tid] = ss; __syncthreads();
    for (int off = 128; off > 0; off >>= 1) {
        if (tid < off) red[tid] += red[tid + off];
        __syncthreads();
    }
    float scale = rsqrtf(red[0] / 4608.f);
    for (int c = tid; c < 512; c += 256) {
        float w9[9]; float s2 = 0.f;
        #pragma unroll
        for (int k = 0; k < 9; k++) { float v = wo[c * 9 + k] * scale; w9[k] = v; s2 += v * v; }
        w2[(size_t)o * 512 + c] = s2;
        #pragma unroll
        for (int k = 0; k < 9; k++) wn[((size_t)k * 512 + o) * 512 + c] = f2bf(w9[k]);
    }
}

// ---------- kernel 3: dcoef[b][o] = rsqrt(sum_c sn^2 * w2 + 1e-8) ----------
__global__ __launch_bounds__(1024) void k_dcoef(const float* __restrict__ sn,
                                                const float* __restrict__ w2,
                                                float* __restrict__ dcoef) {
    __shared__ float sn2[2048];
    int tid = threadIdx.x;
    for (int i = tid; i < 2048; i += 1024) { float v = sn[i]; sn2[i] = v * v; }
    __syncthreads();
    #pragma unroll
    for (int r = 0; r < 2; r++) {
        int idx = tid + r * 1024; int b = idx >> 9; int o = idx & 511;
        const float4* wr = (const float4*)(w2 + (size_t)o * 512);
        const float4* sr = (const float4*)(sn2 + b * 512);
        float acc = 0.f;
        for (int q = 0; q < 128; q++) {
            float4 a = wr[q], s = sr[q];
            acc += a.x * s.x + a.y * s.y + a.z * s.z + a.w * s.w;
        }
        dcoef[idx] = rsqrtf(acc + 1e-8f);
    }
}

// ---------- kernel 4: xpad[b][c][88][88] = bf16(x * sn), zero pad-2 border ----------
__global__ __launch_bounds__(256) void k_premod(const float* __restrict__ x,
                                                const float* __restrict__ sn,
                                                unsigned short* __restrict__ xpad) {
    int bc = blockIdx.x;           // 0..2047
    float s = sn[bc];
    const float* xp = x + (size_t)bc * (HW_ * HW_);
    unsigned short* op = xpad + (size_t)bc * XPIX;
    int tid = threadIdx.x;
    for (int p = tid; p < XPIX / 2; p += 256) {
        int e0 = p * 2;
        int r = e0 / XP_, cc = e0 % XP_;   // cc even
        float v0 = 0.f, v1 = 0.f;
        if (r >= 2 && r < 86) {
            if (cc >= 2 && cc < 86) v0 = xp[(r - 2) * 84 + cc - 2] * s;
            if (cc + 1 >= 2 && cc + 1 < 86) v1 = xp[(r - 2) * 84 + cc - 1] * s;
        }
        unsigned int pk = (unsigned int)f2bf(v0) | ((unsigned int)f2bf(v1) << 16);
        *(unsigned int*)(op + e0) = pk;
    }
}

// ---------- kernel 5: implicit-GEMM conv. BM=64 pixels, BN=128 outputs ----------
__global__ __launch_bounds__(256) void k_conv(const unsigned short* __restrict__ xpad,
                                              const unsigned short* __restrict__ wn,
                                              const float* __restrict__ dcoef,
                                              const float* __restrict__ conv_b,
                                              float* __restrict__ y) {
    __shared__ __align__(16) unsigned short As[64 * 40];   // [pixel][32c + pad8]
    int tid = threadIdx.x;
    int wave = tid >> 6, lane = tid & 63;
    int kgrp = lane >> 4, ln15 = lane & 15;
    int mt = blockIdx.x, ot = blockIdx.y, b = blockIdx.z;
    int m0 = mt * 64;
    int p = lane;
    int m = m0 + p;
    int i = m / HP_, j = m % HP_;       // i may reach 86 on the padded tail
    const unsigned short* xb = xpad + (size_t)b * 512 * XPIX;
    f32x4 acc[2][4];
    #pragma unroll
    for (int t = 0; t < 2; t++)
        #pragma unroll
        for (int g = 0; g < 4; g++) acc[t][g] = (f32x4){0.f, 0.f, 0.f, 0.f};

    #pragma unroll 1
    for (int kh = 0; kh < 3; kh++) {
        #pragma unroll 1
        for (int kw = 0; kw < 3; kw++) {
            int kk = kh * 3 + kw;
            int poff = (i + kh) * XP_ + (j + kw);
            const unsigned short* xs = xb + (size_t)(wave * 8) * XPIX + poff;
            const unsigned short* wk = wn + (size_t)kk * 512 * 512;
            #pragma unroll 1
            for (int c0 = 0; c0 < 512; c0 += 32) {
                const unsigned short* src = xs + (size_t)c0 * XPIX;
                unsigned short u[8];
                #pragma unroll
                for (int e = 0; e < 8; e++) u[e] = src[(size_t)e * XPIX];
                union { bf16x8 v; unsigned int d[4]; } uu;
                uu.d[0] = (unsigned)u[0] | ((unsigned)u[1] << 16);
                uu.d[1] = (unsigned)u[2] | ((unsigned)u[3] << 16);
                uu.d[2] = (unsigned)u[4] | ((unsigned)u[5] << 16);
                uu.d[3] = (unsigned)u[6] | ((unsigned)u[7] << 16);
                __syncthreads();                 // prev iteration's LDS reads done
                *(bf16x8*)&As[p * 40 + wave * 8] = uu.v;
                __syncthreads();                 // writes visible
                const unsigned short* wb = wk + ((size_t)(ot * 128 + wave * 16 + ln15)) * 512 + c0 + kgrp * 8;
                bf16x8 B0 = *(const bf16x8*)wb;
                bf16x8 B1 = *(const bf16x8*)(wb + (size_t)64 * 512);
                #pragma unroll
                for (int g = 0; g < 4; g++) {
                    bf16x8 A = *(const bf16x8*)&As[(g * 16 + ln15) * 40 + kgrp * 8];
                    acc[0][g] = __builtin_amdgcn_mfma_f32_16x16x32_bf16(A, B0, acc[0][g], 0, 0, 0);
                    acc[1][g] = __builtin_amdgcn_mfma_f32_16x16x32_bf16(A, B1, acc[1][g], 0, 0, 0);
                }
            }
        }
    }
    // epilogue: y[b][n][m] = acc * dcoef + bias
    #pragma unroll
    for (int t = 0; t < 2; t++) {
        int n = ot * 128 + t * 64 + wave * 16 + ln15;
        float dc = dcoef[b * 512 + n];
        float bias = conv_b[n];
        float* yp = y + ((size_t)(b * 512 + n)) * NPIX;
        #pragma unroll
        for (int g = 0; g < 4; g++) {
            #pragma unroll
            for (int r = 0; r < 4; r++) {
                int mm = m0 + g * 16 + kgrp * 4 + r;
                if (mm < NPIX) yp[mm] = acc[t][g][r] * dc + bias;
            }
        }
    }
}

// ---------- kernel 6: fused up2 -> leaky*sqrt2 -> clamp -> down2, per (b,o,28x28 tile) ----------
__global__ __launch_bounds__(256) void k_resample(const float* __restrict__ y,
                                                  float* __restrict__ out, Taps taps) {
    __shared__ float yt[38][40];
    __shared__ float upR[66][40];
    __shared__ float upF[66][68];
    __shared__ float dv[28][68];
    int tid = threadIdx.x;
    int tile = blockIdx.x; int o = blockIdx.y; int b = blockIdx.z;
    int tr = (tile / 3) * 28, tc = (tile % 3) * 28;
    const float* yb = y + ((size_t)(b * 512 + o)) * NPIX;

    for (int idx = tid; idx < 38 * 38; idx += 256) {
        int rr = idx / 38, cc = idx % 38;
        int gr = tr - 4 + rr, gc = tc - 4 + cc;
        float v = 0.f;
        if (gr >= 0 && gr < HP_ && gc >= 0 && gc < HP_) v = yb[gr * HP_ + gc];
        yt[rr][cc] = v;
    }
    __syncthreads();
    // vertical upsample (pairs share the 6 source rows)
    for (int idx = tid; idx < 33 * 38; idx += 256) {
        int q = idx / 38, cc = idx % 38;
        float aE = 0.f, aO = 0.f;
        #pragma unroll
        for (int u = 0; u < 6; u++) {
            float v = yt[q + u][cc];
            aE += taps.fu[2 * u + 1] * v;
            aO += taps.fu[2 * u] * v;
        }
        upR[2 * q][cc] = aE; upR[2 * q + 1][cc] = aO;
    }
    __syncthreads();
    // horizontal upsample + leaky*gain + clamp
    for (int idx = tid; idx < 66 * 33; idx += 256) {
        int jr = idx / 33, q = idx % 33;
        float aE = 0.f, aO = 0.f;
        #pragma unroll
        for (int u = 0; u < 6; u++) {
            float v = upR[jr][q + u];
            aE += taps.fu[2 * u + 1] * v;
            aO += taps.fu[2 * u] * v;
        }
        aE = (aE < 0.f ? aE * 0.2f : aE) * 1.4142135623730951f;
        aO = (aO < 0.f ? aO * 0.2f : aO) * 1.4142135623730951f;
        aE = fminf(fmaxf(aE, -256.f), 256.f);
        aO = fminf(fmaxf(aO, -256.f), 256.f);
        float2 pk = make_float2(aE, aO);
        *(float2*)&upF[jr][2 * q] = pk;
    }
    __syncthreads();
    // vertical down
    for (int idx = tid; idx < 28 * 66; idx += 256) {
        int ii = idx / 66, jc = idx % 66;
        float a = 0.f;
        #pragma unroll
        for (int t = 0; t < 12; t++) a += taps.fd[t] * upF[2 * ii + t][jc];
        dv[ii][jc] = a;
    }
    __syncthreads();
    // horizontal down + store
    for (int idx = tid; idx < 28 * 28; idx += 256) {
        int ii = idx / 28, jo = idx % 28;
        float a = 0.f;
        #pragma unroll
        for (int t = 0; t < 12; t++) a += taps.fd[t] * dv[ii][2 * jo + t];
        out[((size_t)(b * 512 + o) * 84 + (tr + ii)) * 84 + (tc + jo)] = a;
    }
}

// ---------- host: replicate the numpy Kaiser lowpass design in double ----------
static double bessel_i0(double x) {
    double s = 1.0, t = 1.0;
    for (int k = 1; k < 60; k++) {
        double u = x / (2.0 * k);
        t *= u * u;
        s += t;
        if (t < 1e-18 * s) break;
    }
    return s;
}

static void design_taps(float* h12) {
    const int N = 12;
    const double cutoff = 16.0, width = 16.0, fs = 128.0;
    double nyq = 0.5 * fs;
    double atten = 2.285 * (N - 1) * M_PI * (width / nyq) + 7.95;
    double beta;
    if (atten > 50.0) beta = 0.1102 * (atten - 8.7);
    else if (atten > 21.0) beta = 0.5842 * pow(atten - 21.0, 0.4) + 0.07886 * (atten - 21.0);
    else beta = 0.0;
    double c = cutoff / nyq;
    double h[12]; double sum = 0.0;
    double ib = bessel_i0(beta);
    for (int n = 0; n < N; n++) {
        double m = n - (N - 1) / 2.0;
        double x = c * m;
        double sinc = (x == 0.0) ? 1.0 : sin(M_PI * x) / (M_PI * x);
        double t = 2.0 * n / (N - 1) - 1.0;
        double arg = 1.0 - t * t; if (arg < 0.0) arg = 0.0;
        double w = bessel_i0(beta * sqrt(arg)) / ib;
        h[n] = c * sinc * w;
        sum += h[n];
    }
    for (int n = 0; n < N; n++) h12[n] = (float)(h[n] / sum);
}

extern "C" void kernel_launch(void* const* d_in, const int* in_sizes, int n_in,
                              void* d_out, int out_size, void* d_ws, size_t ws_size,
                              hipStream_t stream) {
    const float* x      = (const float*)d_in[0];
    const float* wlat   = (const float*)d_in[1];
    const float* aff_w  = (const float*)d_in[2];
    const float* aff_b  = (const float*)d_in[3];
    const float* conv_w = (const float*)d_in[4];
    const float* conv_b = (const float*)d_in[5];
    float* out = (float*)d_out;

    // workspace layout (bytes): sn 8K | dcoef 8K | w2 1M | wn 4.5M | xpad 30.3M | y 57.8M  (~94 MB)
    char* ws = (char*)d_ws;
    float* sn    = (float*)ws;
    float* dcoef = sn + 2048;
    float* w2    = dcoef + 2048;
    unsigned short* wn   = (unsigned short*)(w2 + 512 * 512);
    unsigned short* xpad = wn + (size_t)9 * 512 * 512;
    float* y     = (float*)(xpad + (size_t)B_ * 512 * XPIX);

    Taps taps;
    float h[12];
    design_taps(h);
    for (int t = 0; t < 12; t++) {
        taps.fu[t] = 2.0f * h[11 - t];   // (FU*UP)[::-1]
        taps.fd[t] = h[11 - t];          // FD[::-1]
    }

    k_affine<<<dim3(1), dim3(1024), 0, stream>>>(wlat, aff_w, aff_b, sn);
    k_wprep<<<dim3(512), dim3(256), 0, stream>>>(conv_w, wn, w2);
    k_dcoef<<<dim3(1), dim3(1024), 0, stream>>>(sn, w2, dcoef);
    k_premod<<<dim3(2048), dim3(256), 0, stream>>>(x, sn, xpad);
    k_conv<<<dim3(116, 4, 4), dim3(256), 0, stream>>>(xpad, wn, dcoef, conv_b, y);
    k_resample<<<dim3(9, 512, 4), dim3(256), 0, stream>>>(y, out, taps);
}

// Round 2
// 454.237 us; speedup vs baseline: 1.8617x; 1.8617x over previous
//
#include <hip/hip_runtime.h>
#include <hip/hip_bf16.h>
#include <math.h>

typedef __attribute__((ext_vector_type(8))) short bf16x8;
typedef __attribute__((ext_vector_type(4))) float f32x4;

#define B_    4
#define C_    512
#define HW_   84
#define HP_   86      // conv output spatial (84 + 2*2 - 3 + 1)
#define XP_   88      // zero-padded input spatial
#define NPIX  (HP_*HP_)   // 7396
#define XPIX  (XP_*XP_)   // 7744

struct Taps { float fu[12]; float fd[12]; };

__device__ __forceinline__ unsigned short f2bf(float f) {
    unsigned int u = __float_as_uint(f);
    unsigned int r = (u + 0x7fffu + ((u >> 16) & 1u)) >> 16;   // RNE
    return (unsigned short)r;
}

// ---------- k_s: wave-per-(b,c) dot: s = wlat . (aff_w*g) + aff_b ; partial sum of s^2 ----------
__global__ __launch_bounds__(256) void k_s(const float* __restrict__ wlat,
                                           const float* __restrict__ aff_w,
                                           const float* __restrict__ aff_b,
                                           float* __restrict__ s_raw,
                                           float* __restrict__ parts) {
    int wv = threadIdx.x >> 6, lane = threadIdx.x & 63;
    int w = blockIdx.x * 4 + wv;            // 0..2047
    int b = w >> 9, c = w & 511;
    const float4* aw = (const float4*)(aff_w + (size_t)c * 512);
    const float4* wl = (const float4*)(wlat + b * 512);
    float4 a0 = aw[lane * 2], a1 = aw[lane * 2 + 1];
    float4 w0 = wl[lane * 2], w1 = wl[lane * 2 + 1];
    float acc = a0.x * w0.x + a0.y * w0.y + a0.z * w0.z + a0.w * w0.w
              + a1.x * w1.x + a1.y * w1.y + a1.z * w1.z + a1.w * w1.w;
    #pragma unroll
    for (int m = 1; m < 64; m <<= 1) acc += __shfl_xor(acc, m, 64);
    __shared__ float red[4];
    if (lane == 0) {
        float s = acc * 0.04419417382415922f + aff_b[c];
        s_raw[w] = s; red[wv] = s * s;
    }
    __syncthreads();
    if (threadIdx.x == 0) parts[blockIdx.x] = red[0] + red[1] + red[2] + red[3];
}

// ---------- k_sn: finalize sn = s * rsqrt(mean(s^2)) ----------
__global__ __launch_bounds__(512) void k_sn(const float* __restrict__ s_raw,
                                            const float* __restrict__ parts,
                                            float* __restrict__ sn) {
    __shared__ float red[512];
    int tid = threadIdx.x;
    red[tid] = parts[tid];
    __syncthreads();
    for (int off = 256; off > 0; off >>= 1) {
        if (tid < off) red[tid] += red[tid + off];
        __syncthreads();
    }
    float inv = rsqrtf(red[0] / 2048.f);
    for (int i = tid; i < 2048; i += 512) sn[i] = s_raw[i] * inv;
}

// ---------- k_wprep: weight norm; wn bf16 repack [kk][o][c]; w2[o][c] ----------
__global__ __launch_bounds__(256) void k_wprep(const float* __restrict__ conv_w,
                                               unsigned short* __restrict__ wn,
                                               float* __restrict__ w2) {
    int o = blockIdx.x; int tid = threadIdx.x;
    const float* wo = conv_w + (size_t)o * 4608;
    __shared__ float red[256];
    float ss = 0.f;
    for (int i = tid; i < 4608; i += 256) { float v = wo[i]; ss += v * v; }
    red[tid] = ss; __syncthreads();
    for (int off = 128; off > 0; off >>= 1) {
        if (tid < off) red[tid] += red[tid + off];
        __syncthreads();
    }
    float scale = rsqrtf(red[0] / 4608.f);
    for (int c = tid; c < 512; c += 256) {
        float w9[9]; float s2 = 0.f;
        #pragma unroll
        for (int k = 0; k < 9; k++) { float v = wo[c * 9 + k] * scale; w9[k] = v; s2 += v * v; }
        w2[(size_t)o * 512 + c] = s2;
        #pragma unroll
        for (int k = 0; k < 9; k++) wn[((size_t)k * 512 + o) * 512 + c] = f2bf(w9[k]);
    }
}

// ---------- k_dcoef2: wave-per-(b,o): dcoef = rsqrt(sum_c sn^2*w2 + 1e-8) ----------
__global__ __launch_bounds__(256) void k_dcoef2(const float* __restrict__ sn,
                                                const float* __restrict__ w2,
                                                float* __restrict__ dcoef) {
    int wv = threadIdx.x >> 6, lane = threadIdx.x & 63;
    int w = blockIdx.x * 4 + wv;
    int b = w >> 9, o = w & 511;
    const float4* wr = (const float4*)(w2 + (size_t)o * 512);
    const float4* sr = (const float4*)(sn + b * 512);
    float4 a0 = wr[lane * 2], a1 = wr[lane * 2 + 1];
    float4 s0 = sr[lane * 2], s1 = sr[lane * 2 + 1];
    float acc = a0.x * s0.x * s0.x + a0.y * s0.y * s0.y + a0.z * s0.z * s0.z + a0.w * s0.w * s0.w
              + a1.x * s1.x * s1.x + a1.y * s1.y * s1.y + a1.z * s1.z * s1.z + a1.w * s1.w * s1.w;
    #pragma unroll
    for (int m = 1; m < 64; m <<= 1) acc += __shfl_xor(acc, m, 64);
    if (lane == 0) dcoef[w] = rsqrtf(acc + 1e-8f);
}

// ---------- k_premod2: xpad2[b][cg][88*88][8ch] = bf16(x*sn), zero border ----------
__global__ __launch_bounds__(256) void k_premod2(const float* __restrict__ x,
                                                 const float* __restrict__ sn,
                                                 unsigned short* __restrict__ xpad2) {
    int cg = blockIdx.x, b = blockIdx.y;
    float sv[8];
    #pragma unroll
    for (int e = 0; e < 8; e++) sv[e] = sn[b * 512 + cg * 8 + e];
    const float* xbase = x + ((size_t)(b * 512 + cg * 8)) * (HW_ * HW_);
    unsigned short* op = xpad2 + ((size_t)(b * 64 + cg)) * XPIX * 8;
    for (int pix = threadIdx.x; pix < XPIX; pix += 256) {
        int r = pix / XP_, cc = pix % XP_;
        unsigned int d[4] = {0u, 0u, 0u, 0u};
        if (r >= 2 && r < 86 && cc >= 2 && cc < 86) {
            int off = (r - 2) * HW_ + (cc - 2);
            #pragma unroll
            for (int e = 0; e < 4; e++) {
                unsigned short lo = f2bf(xbase[(size_t)(2 * e) * (HW_ * HW_) + off] * sv[2 * e]);
                unsigned short hi = f2bf(xbase[(size_t)(2 * e + 1) * (HW_ * HW_) + off] * sv[2 * e + 1]);
                d[e] = (unsigned int)lo | ((unsigned int)hi << 16);
            }
        }
        uint4 v; v.x = d[0]; v.y = d[1]; v.z = d[2]; v.w = d[3];
        *(uint4*)(op + (size_t)pix * 8) = v;
    }
}

// ---------- k_conv2: halo-LDS implicit GEMM. tile 8rx16c pixels, BN=256 ----------
// grid (66, 2, 4); 512 threads = 8 waves; wave owns 128 pixels x 32 outputs.
__global__ __launch_bounds__(512, 2) void k_conv2(const unsigned short* __restrict__ xpad2,
                                                  const unsigned short* __restrict__ wn,
                                                  const float* __restrict__ dcoef,
                                                  const float* __restrict__ conv_b,
                                                  float* __restrict__ y) {
    __shared__ __align__(16) unsigned short xwin[180 * 32];   // [pix 10x18][32 ch]
    int tid = threadIdx.x;
    int wv = tid >> 6, lane = tid & 63;
    int kgrp = lane >> 4, ln15 = lane & 15;
    int tile = blockIdx.x, ot = blockIdx.y, b = blockIdx.z;
    int tr = tile / 6, tc = tile % 6;
    int r0 = tr * 8, c0p = tc * 16;
    int obase = ot * 256 + wv * 32;
    const unsigned short* xb = xpad2 + (size_t)b * 64 * XPIX * 8;

    f32x4 acc[8][2];
    #pragma unroll
    for (int g = 0; g < 8; g++) { acc[g][0] = (f32x4){0,0,0,0}; acc[g][1] = (f32x4){0,0,0,0}; }

    int u1 = tid, u2 = 512 + tid;
    bool has2 = tid < 208;

    auto ld = [&](int u, int cc) -> uint4 {
        int cg = cc * 4 + (u & 3);
        int pix = u >> 2;
        int wr = pix / 18, wc = pix - wr * 18;
        int gr = r0 + wr, gc = c0p + wc;
        if (gr < XP_ && gc < XP_)
            return *(const uint4*)(xb + ((size_t)cg * XPIX + gr * XP_ + gc) * 8);
        uint4 z; z.x = z.y = z.z = z.w = 0u; return z;
    };

    uint4 ra = ld(u1, 0);
    uint4 rb; if (has2) rb = ld(u2, 0);

    #pragma unroll 1
    for (int cc = 0; cc < 16; ++cc) {
        __syncthreads();                         // readers of previous chunk done
        *(uint4*)&xwin[u1 * 8] = ra;
        if (has2) *(uint4*)&xwin[u2 * 8] = rb;
        __syncthreads();                         // LDS ready
        if (cc < 15) { ra = ld(u1, cc + 1); if (has2) rb = ld(u2, cc + 1); }
        int c0 = cc * 32;
        #pragma unroll
        for (int kw = 0; kw < 3; ++kw) {
            bf16x8 F[10];
            #pragma unroll
            for (int r = 0; r < 10; ++r)
                F[r] = *(const bf16x8*)&xwin[(r * 18 + ln15 + kw) * 32 + kgrp * 8];
            #pragma unroll
            for (int kh = 0; kh < 3; ++kh) {
                int kk = kh * 3 + kw;
                const unsigned short* wb = wn + ((size_t)(kk * 512) + obase + ln15) * 512 + c0 + kgrp * 8;
                bf16x8 W0 = *(const bf16x8*)wb;
                bf16x8 W1 = *(const bf16x8*)(wb + 16 * 512);
                #pragma unroll
                for (int g = 0; g < 8; ++g) {
                    acc[g][0] = __builtin_amdgcn_mfma_f32_16x16x32_bf16(W0, F[g + kh], acc[g][0], 0, 0, 0);
                    acc[g][1] = __builtin_amdgcn_mfma_f32_16x16x32_bf16(W1, F[g + kh], acc[g][1], 0, 0, 0);
                }
            }
        }
    }

    // epilogue: D row(kgrp*4+r) = o_local, col(ln15) = pixel_local -> coalesced y stores
    float dcv[2][4], bv[2][4];
    #pragma unroll
    for (int nt = 0; nt < 2; nt++)
        #pragma unroll
        for (int r = 0; r < 4; r++) {
            int o = obase + nt * 16 + kgrp * 4 + r;
            dcv[nt][r] = dcoef[b * 512 + o];
            bv[nt][r] = conv_b[o];
        }
    int pcol = c0p + ln15;
    bool colok = pcol < HP_;
    #pragma unroll
    for (int g = 0; g < 8; ++g) {
        int prow = r0 + g;
        if (prow < HP_ && colok) {
            #pragma unroll
            for (int nt = 0; nt < 2; nt++)
                #pragma unroll
                for (int r = 0; r < 4; r++) {
                    int o = obase + nt * 16 + kgrp * 4 + r;
                    y[((size_t)(b * 512 + o)) * NPIX + prow * HP_ + pcol] = acc[g][nt][r] * dcv[nt][r] + bv[nt][r];
                }
        }
    }
}

// ---------- k_resample: fused up2 -> leaky*sqrt2 -> clamp -> down2 (verified round 1) ----------
__global__ __launch_bounds__(256) void k_resample(const float* __restrict__ y,
                                                  float* __restrict__ out, Taps taps) {
    __shared__ float yt[38][40];
    __shared__ float upR[66][40];
    __shared__ float upF[66][68];
    __shared__ float dv[28][68];
    int tid = threadIdx.x;
    int tile = blockIdx.x; int o = blockIdx.y; int b = blockIdx.z;
    int tr = (tile / 3) * 28, tc = (tile % 3) * 28;
    const float* yb = y + ((size_t)(b * 512 + o)) * NPIX;

    for (int idx = tid; idx < 38 * 38; idx += 256) {
        int rr = idx / 38, cc = idx % 38;
        int gr = tr - 4 + rr, gc = tc - 4 + cc;
        float v = 0.f;
        if (gr >= 0 && gr < HP_ && gc >= 0 && gc < HP_) v = yb[gr * HP_ + gc];
        yt[rr][cc] = v;
    }
    __syncthreads();
    for (int idx = tid; idx < 33 * 38; idx += 256) {
        int q = idx / 38, cc = idx % 38;
        float aE = 0.f, aO = 0.f;
        #pragma unroll
        for (int u = 0; u < 6; u++) {
            float v = yt[q + u][cc];
            aE += taps.fu[2 * u + 1] * v;
            aO += taps.fu[2 * u] * v;
        }
        upR[2 * q][cc] = aE; upR[2 * q + 1][cc] = aO;
    }
    __syncthreads();
    for (int idx = tid; idx < 66 * 33; idx += 256) {
        int jr = idx / 33, q = idx % 33;
        float aE = 0.f, aO = 0.f;
        #pragma unroll
        for (int u = 0; u < 6; u++) {
            float v = upR[jr][q + u];
            aE += taps.fu[2 * u + 1] * v;
            aO += taps.fu[2 * u] * v;
        }
        aE = (aE < 0.f ? aE * 0.2f : aE) * 1.4142135623730951f;
        aO = (aO < 0.f ? aO * 0.2f : aO) * 1.4142135623730951f;
        aE = fminf(fmaxf(aE, -256.f), 256.f);
        aO = fminf(fmaxf(aO, -256.f), 256.f);
        float2 pk = make_float2(aE, aO);
        *(float2*)&upF[jr][2 * q] = pk;
    }
    __syncthreads();
    for (int idx = tid; idx < 28 * 66; idx += 256) {
        int ii = idx / 66, jc = idx % 66;
        float a = 0.f;
        #pragma unroll
        for (int t = 0; t < 12; t++) a += taps.fd[t] * upF[2 * ii + t][jc];
        dv[ii][jc] = a;
    }
    __syncthreads();
    for (int idx = tid; idx < 28 * 28; idx += 256) {
        int ii = idx / 28, jo = idx % 28;
        float a = 0.f;
        #pragma unroll
        for (int t = 0; t < 12; t++) a += taps.fd[t] * dv[ii][2 * jo + t];
        out[((size_t)(b * 512 + o) * 84 + (tr + ii)) * 84 + (tc + jo)] = a;
    }
}

// ---------- host: Kaiser lowpass design in double ----------
static double bessel_i0(double x) {
    double s = 1.0, t = 1.0;
    for (int k = 1; k < 60; k++) {
        double u = x / (2.0 * k);
        t *= u * u;
        s += t;
        if (t < 1e-18 * s) break;
    }
    return s;
}

static void design_taps(float* h12) {
    const int N = 12;
    const double cutoff = 16.0, width = 16.0, fs = 128.0;
    double nyq = 0.5 * fs;
    double atten = 2.285 * (N - 1) * M_PI * (width / nyq) + 7.95;
    double beta;
    if (atten > 50.0) beta = 0.1102 * (atten - 8.7);
    else if (atten > 21.0) beta = 0.5842 * pow(atten - 21.0, 0.4) + 0.07886 * (atten - 21.0);
    else beta = 0.0;
    double c = cutoff / nyq;
    double h[12]; double sum = 0.0;
    double ib = bessel_i0(beta);
    for (int n = 0; n < N; n++) {
        double m = n - (N - 1) / 2.0;
        double xx = c * m;
        double sinc = (xx == 0.0) ? 1.0 : sin(M_PI * xx) / (M_PI * xx);
        double t = 2.0 * n / (N - 1) - 1.0;
        double arg = 1.0 - t * t; if (arg < 0.0) arg = 0.0;
        double w = bessel_i0(beta * sqrt(arg)) / ib;
        h[n] = c * sinc * w;
        sum += h[n];
    }
    for (int n = 0; n < N; n++) h12[n] = (float)(h[n] / sum);
}

extern "C" void kernel_launch(void* const* d_in, const int* in_sizes, int n_in,
                              void* d_out, int out_size, void* d_ws, size_t ws_size,
                              hipStream_t stream) {
    const float* x      = (const float*)d_in[0];
    const float* wlat   = (const float*)d_in[1];
    const float* aff_w  = (const float*)d_in[2];
    const float* aff_b  = (const float*)d_in[3];
    const float* conv_w = (const float*)d_in[4];
    const float* conv_b = (const float*)d_in[5];
    float* out = (float*)d_out;

    // ws layout: sn 8K | dcoef 8K | w2 1M | wn 4.5M | xpad2 31.7M | y 60.6M (~93.5 MiB)
    char* ws = (char*)d_ws;
    float* sn    = (float*)ws;
    float* dcoef = sn + 2048;
    float* w2    = dcoef + 2048;
    unsigned short* wn    = (unsigned short*)(w2 + 512 * 512);
    unsigned short* xpad2 = wn + (size_t)9 * 512 * 512;
    float* y     = (float*)(xpad2 + (size_t)B_ * 64 * XPIX * 8);
    // s_raw/parts alias y (consumed before k_conv2 writes y)
    float* s_raw = y;
    float* parts = y + 2048;

    Taps taps;
    float h[12];
    design_taps(h);
    for (int t = 0; t < 12; t++) {
        taps.fu[t] = 2.0f * h[11 - t];   // (FU*UP)[::-1]
        taps.fd[t] = h[11 - t];          // FD[::-1]
    }

    k_s      <<<dim3(512), dim3(256), 0, stream>>>(wlat, aff_w, aff_b, s_raw, parts);
    k_wprep  <<<dim3(512), dim3(256), 0, stream>>>(conv_w, wn, w2);
    k_sn     <<<dim3(1),   dim3(512), 0, stream>>>(s_raw, parts, sn);
    k_dcoef2 <<<dim3(512), dim3(256), 0, stream>>>(sn, w2, dcoef);
    k_premod2<<<dim3(64, 4), dim3(256), 0, stream>>>(x, sn, xpad2);
    k_conv2  <<<dim3(66, 2, 4), dim3(512), 0, stream>>>(xpad2, wn, dcoef, conv_b, y);
    k_resample<<<dim3(9, 512, 4), dim3(256), 0, stream>>>(y, out, taps);
}

// Round 3
// 394.811 us; speedup vs baseline: 2.1419x; 1.1505x over previous
//
#include <hip/hip_runtime.h>
#include <hip/hip_bf16.h>
#include <math.h>

typedef __attribute__((ext_vector_type(8))) short bf16x8;
typedef __attribute__((ext_vector_type(4))) float f32x4;

#define B_    4
#define C_    512
#define HW_   84
#define HP_   86      // conv output spatial (84 + 2*2 - 3 + 1)
#define XP_   88      // zero-padded input spatial
#define NPIX  (HP_*HP_)   // 7396
#define XPIX  (XP_*XP_)   // 7744

struct Taps { float fu[12]; float fd[12]; };

__device__ __forceinline__ unsigned short f2bf(float f) {
    unsigned int u = __float_as_uint(f);
    unsigned int r = (u + 0x7fffu + ((u >> 16) & 1u)) >> 16;   // RNE
    return (unsigned short)r;
}

// ---------- k_s: wave-per-(b,c) dot: s = wlat . (aff_w*g) + aff_b ; partial sum of s^2 ----------
__global__ __launch_bounds__(256) void k_s(const float* __restrict__ wlat,
                                           const float* __restrict__ aff_w,
                                           const float* __restrict__ aff_b,
                                           float* __restrict__ s_raw,
                                           float* __restrict__ parts) {
    int wv = threadIdx.x >> 6, lane = threadIdx.x & 63;
    int w = blockIdx.x * 4 + wv;            // 0..2047
    int b = w >> 9, c = w & 511;
    const float4* aw = (const float4*)(aff_w + (size_t)c * 512);
    const float4* wl = (const float4*)(wlat + b * 512);
    float4 a0 = aw[lane * 2], a1 = aw[lane * 2 + 1];
    float4 w0 = wl[lane * 2], w1 = wl[lane * 2 + 1];
    float acc = a0.x * w0.x + a0.y * w0.y + a0.z * w0.z + a0.w * w0.w
              + a1.x * w1.x + a1.y * w1.y + a1.z * w1.z + a1.w * w1.w;
    #pragma unroll
    for (int m = 1; m < 64; m <<= 1) acc += __shfl_xor(acc, m, 64);
    __shared__ float red[4];
    if (lane == 0) {
        float s = acc * 0.04419417382415922f + aff_b[c];
        s_raw[w] = s; red[wv] = s * s;
    }
    __syncthreads();
    if (threadIdx.x == 0) parts[blockIdx.x] = red[0] + red[1] + red[2] + red[3];
}

// ---------- k_sn: finalize sn = s * rsqrt(mean(s^2)) ----------
__global__ __launch_bounds__(512) void k_sn(const float* __restrict__ s_raw,
                                            const float* __restrict__ parts,
                                            float* __restrict__ sn) {
    __shared__ float red[512];
    int tid = threadIdx.x;
    red[tid] = parts[tid];
    __syncthreads();
    for (int off = 256; off > 0; off >>= 1) {
        if (tid < off) red[tid] += red[tid + off];
        __syncthreads();
    }
    float inv = rsqrtf(red[0] / 2048.f);
    for (int i = tid; i < 2048; i += 512) sn[i] = s_raw[i] * inv;
}

// ---------- k_wprep: weight norm; wn3 bf16 repack [cc][og][o32][kk][c32]; w2[o][c] ----------
__global__ __launch_bounds__(256) void k_wprep(const float* __restrict__ conv_w,
                                               unsigned short* __restrict__ wn3,
                                               float* __restrict__ w2) {
    int o = blockIdx.x; int tid = threadIdx.x;
    const float* wo = conv_w + (size_t)o * 4608;
    __shared__ float red[256];
    float ss = 0.f;
    for (int i = tid; i < 4608; i += 256) { float v = wo[i]; ss += v * v; }
    red[tid] = ss; __syncthreads();
    for (int off = 128; off > 0; off >>= 1) {
        if (tid < off) red[tid] += red[tid + off];
        __syncthreads();
    }
    float scale = rsqrtf(red[0] / 4608.f);
    int og = o >> 5, o32 = o & 31;
    for (int c = tid; c < 512; c += 256) {
        int cc = c >> 5, c32 = c & 31;
        float w9[9]; float s2 = 0.f;
        #pragma unroll
        for (int k = 0; k < 9; k++) { float v = wo[c * 9 + k] * scale; w9[k] = v; s2 += v * v; }
        w2[(size_t)o * 512 + c] = s2;
        size_t base = ((((size_t)cc * 16 + og) * 32 + o32) * 9) * 32 + c32;
        #pragma unroll
        for (int k = 0; k < 9; k++) wn3[base + (size_t)k * 32] = f2bf(w9[k]);
    }
}

// ---------- k_dcoef2: wave-per-(b,o): dcoef = rsqrt(sum_c sn^2*w2 + 1e-8) ----------
__global__ __launch_bounds__(256) void k_dcoef2(const float* __restrict__ sn,
                                                const float* __restrict__ w2,
                                                float* __restrict__ dcoef) {
    int wv = threadIdx.x >> 6, lane = threadIdx.x & 63;
    int w = blockIdx.x * 4 + wv;
    int b = w >> 9, o = w & 511;
    const float4* wr = (const float4*)(w2 + (size_t)o * 512);
    const float4* sr = (const float4*)(sn + b * 512);
    float4 a0 = wr[lane * 2], a1 = wr[lane * 2 + 1];
    float4 s0 = sr[lane * 2], s1 = sr[lane * 2 + 1];
    float acc = a0.x * s0.x * s0.x + a0.y * s0.y * s0.y + a0.z * s0.z * s0.z + a0.w * s0.w * s0.w
              + a1.x * s1.x * s1.x + a1.y * s1.y * s1.y + a1.z * s1.z * s1.z + a1.w * s1.w * s1.w;
    #pragma unroll
    for (int m = 1; m < 64; m <<= 1) acc += __shfl_xor(acc, m, 64);
    if (lane == 0) dcoef[w] = rsqrtf(acc + 1e-8f);
}

// ---------- k_premod2: xpad2[b][cg][88*88][8ch] = bf16(x*sn), zero border ----------
__global__ __launch_bounds__(256) void k_premod2(const float* __restrict__ x,
                                                 const float* __restrict__ sn,
                                                 unsigned short* __restrict__ xpad2) {
    int cg = blockIdx.x, b = blockIdx.y;
    float sv[8];
    #pragma unroll
    for (int e = 0; e < 8; e++) sv[e] = sn[b * 512 + cg * 8 + e];
    const float* xbase = x + ((size_t)(b * 512 + cg * 8)) * (HW_ * HW_);
    unsigned short* op = xpad2 + ((size_t)(b * 64 + cg)) * XPIX * 8;
    for (int pix = threadIdx.x; pix < XPIX; pix += 256) {
        int r = pix / XP_, cc = pix % XP_;
        unsigned int d[4] = {0u, 0u, 0u, 0u};
        if (r >= 2 && r < 86 && cc >= 2 && cc < 86) {
            int off = (r - 2) * HW_ + (cc - 2);
            #pragma unroll
            for (int e = 0; e < 4; e++) {
                unsigned short lo = f2bf(xbase[(size_t)(2 * e) * (HW_ * HW_) + off] * sv[2 * e]);
                unsigned short hi = f2bf(xbase[(size_t)(2 * e + 1) * (HW_ * HW_) + off] * sv[2 * e + 1]);
                d[e] = (unsigned int)lo | ((unsigned int)hi << 16);
            }
        }
        uint4 v; v.x = d[0]; v.y = d[1]; v.z = d[2]; v.w = d[3];
        *(uint4*)(op + (size_t)pix * 8) = v;
    }
}

// ---------- k_conv3: barrier-free implicit GEMM, both operands from L1/L2 ----------
// 1056 blocks (xcd-swizzled), 256 thr = 4 waves. Block: 8x16 pixel tile x 128 outs.
// Wave: 128 pixels x 32 outputs; all 4 waves share the pixel window (L1 dedup).
__global__ __launch_bounds__(256, 3) void k_conv3(const unsigned short* __restrict__ xpad2,
                                                  const unsigned short* __restrict__ wn3,
                                                  const float* __restrict__ dcoef,
                                                  const float* __restrict__ conv_b,
                                                  float* __restrict__ y) {
    // bijective XCD swizzle: consecutive wg on one XCD share weights (ot) and batch
    int bid = blockIdx.x;
    int wg = (bid & 7) * 132 + (bid >> 3);
    int tile = wg % 66; int rest = wg / 66;
    int ot = rest & 3; int b = rest >> 2;

    int tid = threadIdx.x;
    int wv = tid >> 6, lane = tid & 63;
    int kgrp = lane >> 4, ln15 = lane & 15;
    int tr = tile / 6, tc = tile % 6;
    int r0 = tr * 8; if (r0 > 78) r0 = 78;      // clamp: window rows <= 87, outputs all valid
    int c0p = tc * 16; if (c0p > 70) c0p = 70;  // clamp: window cols <= 87
    int og = ot * 4 + wv;

    // pixel fragment base: lane reads pixel (r0+r, c0p+ln15+kw), channels (cc*4+kgrp)*8..+8
    const unsigned short* fb = xpad2 + ((size_t)(b * 64 + kgrp) * XPIX + r0 * XP_ + c0p + ln15) * 8;
    // weight bases (nt = 0/1): element off = (og*32 + nt*16 + ln15)*288 + kgrp*8, + kk*32 per tap
    const unsigned short* wb0 = wn3 + ((size_t)(og * 32 + ln15)) * 288 + kgrp * 8;
    const unsigned short* wb1 = wb0 + (size_t)16 * 288;

    f32x4 acc[8][2];
    #pragma unroll
    for (int g = 0; g < 8; g++) { acc[g][0] = (f32x4){0,0,0,0}; acc[g][1] = (f32x4){0,0,0,0}; }

    #pragma unroll 1
    for (int cc = 0; cc < 16; ++cc) {
        #pragma unroll
        for (int kw = 0; kw < 3; ++kw) {
            bf16x8 F[10];
            #pragma unroll
            for (int r = 0; r < 10; ++r)
                F[r] = *(const bf16x8*)(fb + (r * XP_ + kw) * 8);
            #pragma unroll
            for (int kh = 0; kh < 3; ++kh) {
                int kk = kh * 3 + kw;
                bf16x8 W0 = *(const bf16x8*)(wb0 + kk * 32);
                bf16x8 W1 = *(const bf16x8*)(wb1 + kk * 32);
                #pragma unroll
                for (int g = 0; g < 8; ++g) {
                    acc[g][0] = __builtin_amdgcn_mfma_f32_16x16x32_bf16(W0, F[g + kh], acc[g][0], 0, 0, 0);
                    acc[g][1] = __builtin_amdgcn_mfma_f32_16x16x32_bf16(W1, F[g + kh], acc[g][1], 0, 0, 0);
                }
            }
        }
        fb += (size_t)4 * XPIX * 8;       // next 32-channel chunk
        wb0 += 147456; wb1 += 147456;     // 16*32*288
    }

    // epilogue: D row(kgrp*4+r)=o_local, col(ln15)=pixel_local; all indices in-range by clamp
    float dcv[2][4], bv[2][4];
    #pragma unroll
    for (int nt = 0; nt < 2; nt++)
        #pragma unroll
        for (int r = 0; r < 4; r++) {
            int o = og * 32 + nt * 16 + kgrp * 4 + r;
            dcv[nt][r] = dcoef[b * 512 + o];
            bv[nt][r] = conv_b[o];
        }
    int pcol = c0p + ln15;
    #pragma unroll
    for (int g = 0; g < 8; ++g) {
        int prow = r0 + g;
        #pragma unroll
        for (int nt = 0; nt < 2; nt++)
            #pragma unroll
            for (int r = 0; r < 4; r++) {
                int o = og * 32 + nt * 16 + kgrp * 4 + r;
                y[((size_t)(b * 512 + o)) * NPIX + prow * HP_ + pcol] = acc[g][nt][r] * dcv[nt][r] + bv[nt][r];
            }
    }
}

// ---------- k_resample: fused up2 -> leaky*sqrt2 -> clamp -> down2 (verified) ----------
__global__ __launch_bounds__(256) void k_resample(const float* __restrict__ y,
                                                  float* __restrict__ out, Taps taps) {
    __shared__ float yt[38][40];
    __shared__ float upR[66][40];
    __shared__ float upF[66][68];
    __shared__ float dv[28][68];
    int tid = threadIdx.x;
    int tile = blockIdx.x; int o = blockIdx.y; int b = blockIdx.z;
    int tr = (tile / 3) * 28, tc = (tile % 3) * 28;
    const float* yb = y + ((size_t)(b * 512 + o)) * NPIX;

    for (int idx = tid; idx < 38 * 38; idx += 256) {
        int rr = idx / 38, cc = idx % 38;
        int gr = tr - 4 + rr, gc = tc - 4 + cc;
        float v = 0.f;
        if (gr >= 0 && gr < HP_ && gc >= 0 && gc < HP_) v = yb[gr * HP_ + gc];
        yt[rr][cc] = v;
    }
    __syncthreads();
    for (int idx = tid; idx < 33 * 38; idx += 256) {
        int q = idx / 38, cc = idx % 38;
        float aE = 0.f, aO = 0.f;
        #pragma unroll
        for (int u = 0; u < 6; u++) {
            float v = yt[q + u][cc];
            aE += taps.fu[2 * u + 1] * v;
            aO += taps.fu[2 * u] * v;
        }
        upR[2 * q][cc] = aE; upR[2 * q + 1][cc] = aO;
    }
    __syncthreads();
    for (int idx = tid; idx < 66 * 33; idx += 256) {
        int jr = idx / 33, q = idx % 33;
        float aE = 0.f, aO = 0.f;
        #pragma unroll
        for (int u = 0; u < 6; u++) {
            float v = upR[jr][q + u];
            aE += taps.fu[2 * u + 1] * v;
            aO += taps.fu[2 * u] * v;
        }
        aE = (aE < 0.f ? aE * 0.2f : aE) * 1.4142135623730951f;
        aO = (aO < 0.f ? aO * 0.2f : aO) * 1.4142135623730951f;
        aE = fminf(fmaxf(aE, -256.f), 256.f);
        aO = fminf(fmaxf(aO, -256.f), 256.f);
        float2 pk = make_float2(aE, aO);
        *(float2*)&upF[jr][2 * q] = pk;
    }
    __syncthreads();
    for (int idx = tid; idx < 28 * 66; idx += 256) {
        int ii = idx / 66, jc = idx % 66;
        float a = 0.f;
        #pragma unroll
        for (int t = 0; t < 12; t++) a += taps.fd[t] * upF[2 * ii + t][jc];
        dv[ii][jc] = a;
    }
    __syncthreads();
    for (int idx = tid; idx < 28 * 28; idx += 256) {
        int ii = idx / 28, jo = idx % 28;
        float a = 0.f;
        #pragma unroll
        for (int t = 0; t < 12; t++) a += taps.fd[t] * dv[ii][2 * jo + t];
        out[((size_t)(b * 512 + o) * 84 + (tr + ii)) * 84 + (tc + jo)] = a;
    }
}

// ---------- host: Kaiser lowpass design in double ----------
static double bessel_i0(double x) {
    double s = 1.0, t = 1.0;
    for (int k = 1; k < 60; k++) {
        double u = x / (2.0 * k);
        t *= u * u;
        s += t;
        if (t < 1e-18 * s) break;
    }
    return s;
}

static void design_taps(float* h12) {
    const int N = 12;
    const double cutoff = 16.0, width = 16.0, fs = 128.0;
    double nyq = 0.5 * fs;
    double atten = 2.285 * (N - 1) * M_PI * (width / nyq) + 7.95;
    double beta;
    if (atten > 50.0) beta = 0.1102 * (atten - 8.7);
    else if (atten > 21.0) beta = 0.5842 * pow(atten - 21.0, 0.4) + 0.07886 * (atten - 21.0);
    else beta = 0.0;
    double c = cutoff / nyq;
    double h[12]; double sum = 0.0;
    double ib = bessel_i0(beta);
    for (int n = 0; n < N; n++) {
        double m = n - (N - 1) / 2.0;
        double xx = c * m;
        double sinc = (xx == 0.0) ? 1.0 : sin(M_PI * xx) / (M_PI * xx);
        double t = 2.0 * n / (N - 1) - 1.0;
        double arg = 1.0 - t * t; if (arg < 0.0) arg = 0.0;
        double w = bessel_i0(beta * sqrt(arg)) / ib;
        h[n] = c * sinc * w;
        sum += h[n];
    }
    for (int n = 0; n < N; n++) h12[n] = (float)(h[n] / sum);
}

extern "C" void kernel_launch(void* const* d_in, const int* in_sizes, int n_in,
                              void* d_out, int out_size, void* d_ws, size_t ws_size,
                              hipStream_t stream) {
    const float* x      = (const float*)d_in[0];
    const float* wlat   = (const float*)d_in[1];
    const float* aff_w  = (const float*)d_in[2];
    const float* aff_b  = (const float*)d_in[3];
    const float* conv_w = (const float*)d_in[4];
    const float* conv_b = (const float*)d_in[5];
    float* out = (float*)d_out;

    // ws layout: sn 8K | dcoef 8K | w2 1M | wn3 4.5M | xpad2 31.7M | y 60.6M (~93.5 MiB)
    char* ws = (char*)d_ws;
    float* sn    = (float*)ws;
    float* dcoef = sn + 2048;
    float* w2    = dcoef + 2048;
    unsigned short* wn3   = (unsigned short*)(w2 + 512 * 512);
    unsigned short* xpad2 = wn3 + (size_t)9 * 512 * 512;
    float* y     = (float*)(xpad2 + (size_t)B_ * 64 * XPIX * 8);
    // s_raw/parts alias y (consumed before k_conv3 writes y)
    float* s_raw = y;
    float* parts = y + 2048;

    Taps taps;
    float h[12];
    design_taps(h);
    for (int t = 0; t < 12; t++) {
        taps.fu[t] = 2.0f * h[11 - t];   // (FU*UP)[::-1]
        taps.fd[t] = h[11 - t];          // FD[::-1]
    }

    k_s      <<<dim3(512), dim3(256), 0, stream>>>(wlat, aff_w, aff_b, s_raw, parts);
    k_wprep  <<<dim3(512), dim3(256), 0, stream>>>(conv_w, wn3, w2);
    k_sn     <<<dim3(1),   dim3(512), 0, stream>>>(s_raw, parts, sn);
    k_dcoef2 <<<dim3(512), dim3(256), 0, stream>>>(sn, w2, dcoef);
    k_premod2<<<dim3(64, 4), dim3(256), 0, stream>>>(x, sn, xpad2);
    k_conv3  <<<dim3(1056), dim3(256), 0, stream>>>(xpad2, wn3, dcoef, conv_b, y);
    k_resample<<<dim3(9, 512, 4), dim3(256), 0, stream>>>(y, out, taps);
}

// Round 4
// 373.226 us; speedup vs baseline: 2.2657x; 1.0578x over previous
//
#include <hip/hip_runtime.h>
#include <hip/hip_bf16.h>
#include <math.h>

typedef __attribute__((ext_vector_type(8))) short bf16x8;
typedef __attribute__((ext_vector_type(4))) float f32x4;

#define B_    4
#define C_    512
#define HW_   84
#define HP_   86      // conv output spatial (84 + 2*2 - 3 + 1)
#define XP_   88      // zero-padded input spatial
#define NPIX  (HP_*HP_)   // 7396
#define XPIX  (XP_*XP_)   // 7744
#define YSEG  ((size_t)2048 * NPIX)   // elements per partial buffer

struct Taps { float fu[12]; float fd[12]; };

__device__ __forceinline__ unsigned short f2bf(float f) {
    unsigned int u = __float_as_uint(f);
    unsigned int r = (u + 0x7fffu + ((u >> 16) & 1u)) >> 16;   // RNE
    return (unsigned short)r;
}
__device__ __forceinline__ float bf2f(unsigned short u) {
    return __uint_as_float((unsigned int)u << 16);
}

// ---------- k_s: wave-per-(b,c) dot: s = wlat . (aff_w*g) + aff_b ; partial sum of s^2 ----------
__global__ __launch_bounds__(256) void k_s(const float* __restrict__ wlat,
                                           const float* __restrict__ aff_w,
                                           const float* __restrict__ aff_b,
                                           float* __restrict__ s_raw,
                                           float* __restrict__ parts) {
    int wv = threadIdx.x >> 6, lane = threadIdx.x & 63;
    int w = blockIdx.x * 4 + wv;            // 0..2047
    int b = w >> 9, c = w & 511;
    const float4* aw = (const float4*)(aff_w + (size_t)c * 512);
    const float4* wl = (const float4*)(wlat + b * 512);
    float4 a0 = aw[lane * 2], a1 = aw[lane * 2 + 1];
    float4 w0 = wl[lane * 2], w1 = wl[lane * 2 + 1];
    float acc = a0.x * w0.x + a0.y * w0.y + a0.z * w0.z + a0.w * w0.w
              + a1.x * w1.x + a1.y * w1.y + a1.z * w1.z + a1.w * w1.w;
    #pragma unroll
    for (int m = 1; m < 64; m <<= 1) acc += __shfl_xor(acc, m, 64);
    __shared__ float red[4];
    if (lane == 0) {
        float s = acc * 0.04419417382415922f + aff_b[c];
        s_raw[w] = s; red[wv] = s * s;
    }
    __syncthreads();
    if (threadIdx.x == 0) parts[blockIdx.x] = red[0] + red[1] + red[2] + red[3];
}

// ---------- k_wprep: weight norm; wn3 bf16 repack [cc][og][o32][kk][c32]; w2[o][c] ----------
__global__ __launch_bounds__(256) void k_wprep(const float* __restrict__ conv_w,
                                               unsigned short* __restrict__ wn3,
                                               float* __restrict__ w2) {
    int o = blockIdx.x; int tid = threadIdx.x;
    const float* wo = conv_w + (size_t)o * 4608;
    __shared__ float red[256];
    float ss = 0.f;
    for (int i = tid; i < 4608; i += 256) { float v = wo[i]; ss += v * v; }
    red[tid] = ss; __syncthreads();
    for (int off = 128; off > 0; off >>= 1) {
        if (tid < off) red[tid] += red[tid + off];
        __syncthreads();
    }
    float scale = rsqrtf(red[0] / 4608.f);
    int og = o >> 5, o32 = o & 31;
    for (int c = tid; c < 512; c += 256) {
        int cc = c >> 5, c32 = c & 31;
        float w9[9]; float s2 = 0.f;
        #pragma unroll
        for (int k = 0; k < 9; k++) { float v = wo[c * 9 + k] * scale; w9[k] = v; s2 += v * v; }
        w2[(size_t)o * 512 + c] = s2;
        size_t base = ((((size_t)cc * 16 + og) * 32 + o32) * 9) * 32 + c32;
        #pragma unroll
        for (int k = 0; k < 9; k++) wn3[base + (size_t)k * 32] = f2bf(w9[k]);
    }
}

// ---------- k_dcoef3: wave-per-(b,o): reduce parts -> inv; dcoef + sn write ----------
__global__ __launch_bounds__(256) void k_dcoef3(const float* __restrict__ s_raw,
                                                const float* __restrict__ parts,
                                                const float* __restrict__ w2,
                                                float* __restrict__ sn,
                                                float* __restrict__ dcoef) {
    int wv = threadIdx.x >> 6, lane = threadIdx.x & 63;
    int w = blockIdx.x * 4 + wv;
    int b = w >> 9, o = w & 511;
    const float4* pp = (const float4*)parts;
    float4 p0 = pp[lane * 2], p1 = pp[lane * 2 + 1];
    float tot = p0.x + p0.y + p0.z + p0.w + p1.x + p1.y + p1.z + p1.w;
    #pragma unroll
    for (int m = 1; m < 64; m <<= 1) tot += __shfl_xor(tot, m, 64);
    float inv = rsqrtf(tot / 2048.f);
    const float4* sr = (const float4*)(s_raw + b * 512);
    const float4* wr = (const float4*)(w2 + (size_t)o * 512);
    float acc = 0.f;
    #pragma unroll
    for (int q = 0; q < 2; q++) {
        float4 s = sr[lane * 2 + q], ww = wr[lane * 2 + q];
        float s0 = s.x * inv, s1 = s.y * inv, s2 = s.z * inv, s3 = s.w * inv;
        acc += ww.x * s0 * s0 + ww.y * s1 * s1 + ww.z * s2 * s2 + ww.w * s3 * s3;
    }
    #pragma unroll
    for (int m = 1; m < 64; m <<= 1) acc += __shfl_xor(acc, m, 64);
    if (lane == 0) {
        dcoef[w] = rsqrtf(acc + 1e-8f);
        sn[w] = s_raw[w] * inv;
    }
}

// ---------- k_premod2: xpad2[b][cg][88*88][8ch] = bf16(x*sn), zero border ----------
__global__ __launch_bounds__(256) void k_premod2(const float* __restrict__ x,
                                                 const float* __restrict__ sn,
                                                 unsigned short* __restrict__ xpad2) {
    int cg = blockIdx.x, b = blockIdx.y;
    float sv[8];
    #pragma unroll
    for (int e = 0; e < 8; e++) sv[e] = sn[b * 512 + cg * 8 + e];
    const float* xbase = x + ((size_t)(b * 512 + cg * 8)) * (HW_ * HW_);
    unsigned short* op = xpad2 + ((size_t)(b * 64 + cg)) * XPIX * 8;
    for (int pix = threadIdx.x; pix < XPIX; pix += 256) {
        int r = pix / XP_, cc = pix % XP_;
        unsigned int d[4] = {0u, 0u, 0u, 0u};
        if (r >= 2 && r < 86 && cc >= 2 && cc < 86) {
            int off = (r - 2) * HW_ + (cc - 2);
            #pragma unroll
            for (int e = 0; e < 4; e++) {
                unsigned short lo = f2bf(xbase[(size_t)(2 * e) * (HW_ * HW_) + off] * sv[2 * e]);
                unsigned short hi = f2bf(xbase[(size_t)(2 * e + 1) * (HW_ * HW_) + off] * sv[2 * e + 1]);
                d[e] = (unsigned int)lo | ((unsigned int)hi << 16);
            }
        }
        uint4 v; v.x = d[0]; v.y = d[1]; v.z = d[2]; v.w = d[3];
        *(uint4*)(op + (size_t)pix * 8) = v;
    }
}

// ---------- k_conv4: K-split barrier-free implicit GEMM, bf16 partial outputs ----------
// 2112 blocks (xcd-swizzled), 256 thr = 4 waves. Block: 8x16 pixel tile x 128 outs x half-K.
__global__ __launch_bounds__(256, 3) void k_conv4(const unsigned short* __restrict__ xpad2,
                                                  const unsigned short* __restrict__ wn3,
                                                  const float* __restrict__ dcoef,
                                                  const float* __restrict__ conv_b,
                                                  unsigned short* __restrict__ ypart) {
    // bijective XCD swizzle (2112 % 8 == 0, cpx = 264): each XCD gets fixed (b,seg), ot 0..3
    int bid = blockIdx.x;
    int wg = (bid & 7) * 264 + (bid >> 3);
    int tile = wg % 66; int rest = wg / 66;       // rest = b*8 + seg*4 + ot
    int ot = rest & 3; int seg = (rest >> 2) & 1; int b = rest >> 3;

    int tid = threadIdx.x;
    int wv = tid >> 6, lane = tid & 63;
    int kgrp = lane >> 4, ln15 = lane & 15;
    int tr = tile / 6, tc = tile % 6;
    int r0 = tr * 8; if (r0 > 78) r0 = 78;      // clamp: window rows <= 87, outputs all valid
    int c0p = tc * 16; if (c0p > 70) c0p = 70;  // clamp: window cols <= 87
    int og = ot * 4 + wv;

    // pixel fragment base: channels (seg*32 + cc*4 + kgrp)*8..+8
    const unsigned short* fb = xpad2 + ((size_t)(b * 64 + seg * 32 + kgrp) * XPIX + r0 * XP_ + c0p + ln15) * 8;
    // weight bases, offset by seg half of cc
    const unsigned short* wb0 = wn3 + (size_t)(seg * 8) * 147456 + ((size_t)(og * 32 + ln15)) * 288 + kgrp * 8;
    const unsigned short* wb1 = wb0 + (size_t)16 * 288;

    f32x4 acc[8][2];
    #pragma unroll
    for (int g = 0; g < 8; g++) { acc[g][0] = (f32x4){0,0,0,0}; acc[g][1] = (f32x4){0,0,0,0}; }

    #pragma unroll 1
    for (int cc = 0; cc < 8; ++cc) {
        #pragma unroll
        for (int kw = 0; kw < 3; ++kw) {
            bf16x8 F[10];
            #pragma unroll
            for (int r = 0; r < 10; ++r)
                F[r] = *(const bf16x8*)(fb + (r * XP_ + kw) * 8);
            #pragma unroll
            for (int kh = 0; kh < 3; ++kh) {
                int kk = kh * 3 + kw;
                bf16x8 W0 = *(const bf16x8*)(wb0 + kk * 32);
                bf16x8 W1 = *(const bf16x8*)(wb1 + kk * 32);
                #pragma unroll
                for (int g = 0; g < 8; ++g) {
                    acc[g][0] = __builtin_amdgcn_mfma_f32_16x16x32_bf16(W0, F[g + kh], acc[g][0], 0, 0, 0);
                    acc[g][1] = __builtin_amdgcn_mfma_f32_16x16x32_bf16(W1, F[g + kh], acc[g][1], 0, 0, 0);
                }
            }
        }
        fb += (size_t)4 * XPIX * 8;       // next 32-channel chunk
        wb0 += 147456; wb1 += 147456;     // 16*32*288
    }

    // epilogue: partial = acc*dcoef (+bias on seg 1), bf16 store
    float dcv[2][4], bvs[2][4];
    #pragma unroll
    for (int nt = 0; nt < 2; nt++)
        #pragma unroll
        for (int r = 0; r < 4; r++) {
            int o = og * 32 + nt * 16 + kgrp * 4 + r;
            dcv[nt][r] = dcoef[b * 512 + o];
            bvs[nt][r] = seg ? conv_b[o] : 0.f;
        }
    unsigned short* yp = ypart + (size_t)seg * YSEG;
    int pcol = c0p + ln15;
    #pragma unroll
    for (int g = 0; g < 8; ++g) {
        int prow = r0 + g;
        #pragma unroll
        for (int nt = 0; nt < 2; nt++)
            #pragma unroll
            for (int r = 0; r < 4; r++) {
                int o = og * 32 + nt * 16 + kgrp * 4 + r;
                yp[((size_t)(b * 512 + o)) * NPIX + prow * HP_ + pcol] =
                    f2bf(acc[g][nt][r] * dcv[nt][r] + bvs[nt][r]);
            }
    }
}

// ---------- k_resample: combine partials + fused up2 -> leaky*sqrt2 -> clamp -> down2 ----------
__global__ __launch_bounds__(256) void k_resample(const unsigned short* __restrict__ ypart,
                                                  float* __restrict__ out, Taps taps) {
    __shared__ float yt[38][40];
    __shared__ float upR[66][40];
    __shared__ float upF[66][68];
    __shared__ float dv[28][68];
    int tid = threadIdx.x;
    int tile = blockIdx.x; int o = blockIdx.y; int b = blockIdx.z;
    int tr = (tile / 3) * 28, tc = (tile % 3) * 28;
    const unsigned short* y0b = ypart + ((size_t)(b * 512 + o)) * NPIX;
    const unsigned short* y1b = y0b + YSEG;

    for (int idx = tid; idx < 38 * 38; idx += 256) {
        int rr = idx / 38, cc = idx % 38;
        int gr = tr - 4 + rr, gc = tc - 4 + cc;
        float v = 0.f;
        if (gr >= 0 && gr < HP_ && gc >= 0 && gc < HP_) {
            int p = gr * HP_ + gc;
            v = bf2f(y0b[p]) + bf2f(y1b[p]);
        }
        yt[rr][cc] = v;
    }
    __syncthreads();
    for (int idx = tid; idx < 33 * 38; idx += 256) {
        int q = idx / 38, cc = idx % 38;
        float aE = 0.f, aO = 0.f;
        #pragma unroll
        for (int u = 0; u < 6; u++) {
            float v = yt[q + u][cc];
            aE += taps.fu[2 * u + 1] * v;
            aO += taps.fu[2 * u] * v;
        }
        upR[2 * q][cc] = aE; upR[2 * q + 1][cc] = aO;
    }
    __syncthreads();
    for (int idx = tid; idx < 66 * 33; idx += 256) {
        int jr = idx / 33, q = idx % 33;
        float aE = 0.f, aO = 0.f;
        #pragma unroll
        for (int u = 0; u < 6; u++) {
            float v = upR[jr][q + u];
            aE += taps.fu[2 * u + 1] * v;
            aO += taps.fu[2 * u] * v;
        }
        aE = (aE < 0.f ? aE * 0.2f : aE) * 1.4142135623730951f;
        aO = (aO < 0.f ? aO * 0.2f : aO) * 1.4142135623730951f;
        aE = fminf(fmaxf(aE, -256.f), 256.f);
        aO = fminf(fmaxf(aO, -256.f), 256.f);
        float2 pk = make_float2(aE, aO);
        *(float2*)&upF[jr][2 * q] = pk;
    }
    __syncthreads();
    for (int idx = tid; idx < 28 * 66; idx += 256) {
        int ii = idx / 66, jc = idx % 66;
        float a = 0.f;
        #pragma unroll
        for (int t = 0; t < 12; t++) a += taps.fd[t] * upF[2 * ii + t][jc];
        dv[ii][jc] = a;
    }
    __syncthreads();
    for (int idx = tid; idx < 28 * 28; idx += 256) {
        int ii = idx / 28, jo = idx % 28;
        float a = 0.f;
        #pragma unroll
        for (int t = 0; t < 12; t++) a += taps.fd[t] * dv[ii][2 * jo + t];
        out[((size_t)(b * 512 + o) * 84 + (tr + ii)) * 84 + (tc + jo)] = a;
    }
}

// ---------- host: Kaiser lowpass design in double ----------
static double bessel_i0(double x) {
    double s = 1.0, t = 1.0;
    for (int k = 1; k < 60; k++) {
        double u = x / (2.0 * k);
        t *= u * u;
        s += t;
        if (t < 1e-18 * s) break;
    }
    return s;
}

static void design_taps(float* h12) {
    const int N = 12;
    const double cutoff = 16.0, width = 16.0, fs = 128.0;
    double nyq = 0.5 * fs;
    double atten = 2.285 * (N - 1) * M_PI * (width / nyq) + 7.95;
    double beta;
    if (atten > 50.0) beta = 0.1102 * (atten - 8.7);
    else if (atten > 21.0) beta = 0.5842 * pow(atten - 21.0, 0.4) + 0.07886 * (atten - 21.0);
    else beta = 0.0;
    double c = cutoff / nyq;
    double h[12]; double sum = 0.0;
    double ib = bessel_i0(beta);
    for (int n = 0; n < N; n++) {
        double m = n - (N - 1) / 2.0;
        double xx = c * m;
        double sinc = (xx == 0.0) ? 1.0 : sin(M_PI * xx) / (M_PI * xx);
        double t = 2.0 * n / (N - 1) - 1.0;
        double arg = 1.0 - t * t; if (arg < 0.0) arg = 0.0;
        double w = bessel_i0(beta * sqrt(arg)) / ib;
        h[n] = c * sinc * w;
        sum += h[n];
    }
    for (int n = 0; n < N; n++) h12[n] = (float)(h[n] / sum);
}

extern "C" void kernel_launch(void* const* d_in, const int* in_sizes, int n_in,
                              void* d_out, int out_size, void* d_ws, size_t ws_size,
                              hipStream_t stream) {
    const float* x      = (const float*)d_in[0];
    const float* wlat   = (const float*)d_in[1];
    const float* aff_w  = (const float*)d_in[2];
    const float* aff_b  = (const float*)d_in[3];
    const float* conv_w = (const float*)d_in[4];
    const float* conv_b = (const float*)d_in[5];
    float* out = (float*)d_out;

    // ws layout: sn 8K | dcoef 8K | w2 1M | wn3 4.5M | xpad2 31.7M | ypart 60.6M (~98 MiB)
    char* ws = (char*)d_ws;
    float* sn    = (float*)ws;
    float* dcoef = sn + 2048;
    float* w2    = dcoef + 2048;
    unsigned short* wn3   = (unsigned short*)(w2 + 512 * 512);
    unsigned short* xpad2 = wn3 + (size_t)9 * 512 * 512;
    unsigned short* ypart = xpad2 + (size_t)B_ * 64 * XPIX * 8;
    // s_raw/parts alias ypart (consumed by k_dcoef3 before k_conv4 writes)
    float* s_raw = (float*)ypart;
    float* parts = s_raw + 2048;

    Taps taps;
    float h[12];
    design_taps(h);
    for (int t = 0; t < 12; t++) {
        taps.fu[t] = 2.0f * h[11 - t];   // (FU*UP)[::-1]
        taps.fd[t] = h[11 - t];          // FD[::-1]
    }

    k_s      <<<dim3(512), dim3(256), 0, stream>>>(wlat, aff_w, aff_b, s_raw, parts);
    k_wprep  <<<dim3(512), dim3(256), 0, stream>>>(conv_w, wn3, w2);
    k_dcoef3 <<<dim3(512), dim3(256), 0, stream>>>(s_raw, parts, w2, sn, dcoef);
    k_premod2<<<dim3(64, 4), dim3(256), 0, stream>>>(x, sn, xpad2);
    k_conv4  <<<dim3(2112), dim3(256), 0, stream>>>(xpad2, wn3, dcoef, conv_b, ypart);
    k_resample<<<dim3(9, 512, 4), dim3(256), 0, stream>>>(ypart, out, taps);
}

// Round 5
// 311.926 us; speedup vs baseline: 2.7110x; 1.1965x over previous
//
#include <hip/hip_runtime.h>
#include <hip/hip_bf16.h>
#include <math.h>

typedef __attribute__((ext_vector_type(8))) short bf16x8;
typedef __attribute__((ext_vector_type(4))) float f32x4;

#define B_    4
#define C_    512
#define HW_   84
#define HP_   86      // conv output spatial (84 + 2*2 - 3 + 1)
#define XP_   88      // zero-padded input spatial
#define NPIX  (HP_*HP_)   // 7396
#define XPIX  (XP_*XP_)   // 7744
#define YSEG  ((size_t)2048 * NPIX)   // elements per partial buffer

struct Taps { float fu[12]; float fd[12]; };

__device__ __forceinline__ unsigned short f2bf(float f) {
    unsigned int u = __float_as_uint(f);
    unsigned int r = (u + 0x7fffu + ((u >> 16) & 1u)) >> 16;   // RNE
    return (unsigned short)r;
}
__device__ __forceinline__ float bf2f(unsigned short u) {
    return __uint_as_float((unsigned int)u << 16);
}

// ---------- k_prep: blocks 0..511 -> k_s work; 512..1023 -> k_wprep work ----------
__global__ __launch_bounds__(256) void k_prep(const float* __restrict__ wlat,
                                              const float* __restrict__ aff_w,
                                              const float* __restrict__ aff_b,
                                              const float* __restrict__ conv_w,
                                              float* __restrict__ s_raw,
                                              float* __restrict__ parts,
                                              unsigned short* __restrict__ wn3,
                                              float* __restrict__ w2) {
    __shared__ float red[256];
    int tid = threadIdx.x;
    if (blockIdx.x < 512) {
        // ---- affine s ----
        int wv = tid >> 6, lane = tid & 63;
        int w = blockIdx.x * 4 + wv;            // 0..2047
        int b = w >> 9, c = w & 511;
        const float4* aw = (const float4*)(aff_w + (size_t)c * 512);
        const float4* wl = (const float4*)(wlat + b * 512);
        float4 a0 = aw[lane * 2], a1 = aw[lane * 2 + 1];
        float4 w0 = wl[lane * 2], w1 = wl[lane * 2 + 1];
        float acc = a0.x * w0.x + a0.y * w0.y + a0.z * w0.z + a0.w * w0.w
                  + a1.x * w1.x + a1.y * w1.y + a1.z * w1.z + a1.w * w1.w;
        #pragma unroll
        for (int m = 1; m < 64; m <<= 1) acc += __shfl_xor(acc, m, 64);
        if (lane == 0) {
            float s = acc * 0.04419417382415922f + aff_b[c];
            s_raw[w] = s; red[wv] = s * s;
        }
        __syncthreads();
        if (tid == 0) parts[blockIdx.x] = red[0] + red[1] + red[2] + red[3];
    } else {
        // ---- weight norm + repack ----
        int o = blockIdx.x - 512;
        const float* wo = conv_w + (size_t)o * 4608;
        float ss = 0.f;
        for (int i = tid; i < 4608; i += 256) { float v = wo[i]; ss += v * v; }
        red[tid] = ss; __syncthreads();
        for (int off = 128; off > 0; off >>= 1) {
            if (tid < off) red[tid] += red[tid + off];
            __syncthreads();
        }
        float scale = rsqrtf(red[0] / 4608.f);
        int og = o >> 5, o32 = o & 31;
        for (int c = tid; c < 512; c += 256) {
            int cc = c >> 5, c32 = c & 31;
            float w9[9]; float s2 = 0.f;
            #pragma unroll
            for (int k = 0; k < 9; k++) { float v = wo[c * 9 + k] * scale; w9[k] = v; s2 += v * v; }
            w2[(size_t)o * 512 + c] = s2;
            size_t base = ((((size_t)cc * 16 + og) * 32 + o32) * 9) * 32 + c32;
            #pragma unroll
            for (int k = 0; k < 9; k++) wn3[base + (size_t)k * 32] = f2bf(w9[k]);
        }
    }
}

// ---------- k_dcoef3: wave-per-(b,o): reduce parts -> inv; dcoef + sn write ----------
__global__ __launch_bounds__(256) void k_dcoef3(const float* __restrict__ s_raw,
                                                const float* __restrict__ parts,
                                                const float* __restrict__ w2,
                                                float* __restrict__ sn,
                                                float* __restrict__ dcoef) {
    int wv = threadIdx.x >> 6, lane = threadIdx.x & 63;
    int w = blockIdx.x * 4 + wv;
    int b = w >> 9, o = w & 511;
    const float4* pp = (const float4*)parts;
    float4 p0 = pp[lane * 2], p1 = pp[lane * 2 + 1];
    float tot = p0.x + p0.y + p0.z + p0.w + p1.x + p1.y + p1.z + p1.w;
    #pragma unroll
    for (int m = 1; m < 64; m <<= 1) tot += __shfl_xor(tot, m, 64);
    float inv = rsqrtf(tot / 2048.f);
    const float4* sr = (const float4*)(s_raw + b * 512);
    const float4* wr = (const float4*)(w2 + (size_t)o * 512);
    float acc = 0.f;
    #pragma unroll
    for (int q = 0; q < 2; q++) {
        float4 s = sr[lane * 2 + q], ww = wr[lane * 2 + q];
        float s0 = s.x * inv, s1 = s.y * inv, s2 = s.z * inv, s3 = s.w * inv;
        acc += ww.x * s0 * s0 + ww.y * s1 * s1 + ww.z * s2 * s2 + ww.w * s3 * s3;
    }
    #pragma unroll
    for (int m = 1; m < 64; m <<= 1) acc += __shfl_xor(acc, m, 64);
    if (lane == 0) {
        dcoef[w] = rsqrtf(acc + 1e-8f);
        sn[w] = s_raw[w] * inv;
    }
}

// ---------- k_premod2: xpad2[b][cg][88*88][8ch] = bf16(x*sn), zero border ----------
__global__ __launch_bounds__(256) void k_premod2(const float* __restrict__ x,
                                                 const float* __restrict__ sn,
                                                 unsigned short* __restrict__ xpad2) {
    int cg = blockIdx.x >> 1, half = blockIdx.x & 1, b = blockIdx.y;
    float sv[8];
    #pragma unroll
    for (int e = 0; e < 8; e++) sv[e] = sn[b * 512 + cg * 8 + e];
    const float* xbase = x + ((size_t)(b * 512 + cg * 8)) * (HW_ * HW_);
    unsigned short* op = xpad2 + ((size_t)(b * 64 + cg)) * XPIX * 8;
    int p0 = half * (XPIX / 2), p1 = p0 + XPIX / 2;
    for (int pix = p0 + threadIdx.x; pix < p1; pix += 256) {
        int r = pix / XP_, cc = pix % XP_;
        unsigned int d[4] = {0u, 0u, 0u, 0u};
        if (r >= 2 && r < 86 && cc >= 2 && cc < 86) {
            int off = (r - 2) * HW_ + (cc - 2);
            #pragma unroll
            for (int e = 0; e < 4; e++) {
                unsigned short lo = f2bf(xbase[(size_t)(2 * e) * (HW_ * HW_) + off] * sv[2 * e]);
                unsigned short hi = f2bf(xbase[(size_t)(2 * e + 1) * (HW_ * HW_) + off] * sv[2 * e + 1]);
                d[e] = (unsigned int)lo | ((unsigned int)hi << 16);
            }
        }
        uint4 v; v.x = d[0]; v.y = d[1]; v.z = d[2]; v.w = d[3];
        *(uint4*)(op + (size_t)pix * 8) = v;
    }
}

// ---------- k_conv4: K-split barrier-free implicit GEMM, bf16 partial outputs ----------
// 2112 blocks (xcd-swizzled), 256 thr = 4 waves. Block: 8x16 pixel tile x 128 outs x half-K.
__global__ __launch_bounds__(256, 3) void k_conv4(const unsigned short* __restrict__ xpad2,
                                                  const unsigned short* __restrict__ wn3,
                                                  const float* __restrict__ dcoef,
                                                  const float* __restrict__ conv_b,
                                                  unsigned short* __restrict__ ypart) {
    int bid = blockIdx.x;
    int wg = (bid & 7) * 264 + (bid >> 3);
    int tile = wg % 66; int rest = wg / 66;       // rest = b*8 + seg*4 + ot
    int ot = rest & 3; int seg = (rest >> 2) & 1; int b = rest >> 3;

    int tid = threadIdx.x;
    int wv = tid >> 6, lane = tid & 63;
    int kgrp = lane >> 4, ln15 = lane & 15;
    int tr = tile / 6, tc = tile % 6;
    int r0 = tr * 8; if (r0 > 78) r0 = 78;
    int c0p = tc * 16; if (c0p > 70) c0p = 70;
    int og = ot * 4 + wv;

    const unsigned short* fb = xpad2 + ((size_t)(b * 64 + seg * 32 + kgrp) * XPIX + r0 * XP_ + c0p + ln15) * 8;
    const unsigned short* wb0 = wn3 + (size_t)(seg * 8) * 147456 + ((size_t)(og * 32 + ln15)) * 288 + kgrp * 8;
    const unsigned short* wb1 = wb0 + (size_t)16 * 288;

    f32x4 acc[8][2];
    #pragma unroll
    for (int g = 0; g < 8; g++) { acc[g][0] = (f32x4){0,0,0,0}; acc[g][1] = (f32x4){0,0,0,0}; }

    #pragma unroll 1
    for (int cc = 0; cc < 8; ++cc) {
        #pragma unroll
        for (int kw = 0; kw < 3; ++kw) {
            bf16x8 F[10];
            #pragma unroll
            for (int r = 0; r < 10; ++r)
                F[r] = *(const bf16x8*)(fb + (r * XP_ + kw) * 8);
            #pragma unroll
            for (int kh = 0; kh < 3; ++kh) {
                int kk = kh * 3 + kw;
                bf16x8 W0 = *(const bf16x8*)(wb0 + kk * 32);
                bf16x8 W1 = *(const bf16x8*)(wb1 + kk * 32);
                #pragma unroll
                for (int g = 0; g < 8; ++g) {
                    acc[g][0] = __builtin_amdgcn_mfma_f32_16x16x32_bf16(W0, F[g + kh], acc[g][0], 0, 0, 0);
                    acc[g][1] = __builtin_amdgcn_mfma_f32_16x16x32_bf16(W1, F[g + kh], acc[g][1], 0, 0, 0);
                }
            }
        }
        fb += (size_t)4 * XPIX * 8;
        wb0 += 147456; wb1 += 147456;
    }

    float dcv[2][4], bvs[2][4];
    #pragma unroll
    for (int nt = 0; nt < 2; nt++)
        #pragma unroll
        for (int r = 0; r < 4; r++) {
            int o = og * 32 + nt * 16 + kgrp * 4 + r;
            dcv[nt][r] = dcoef[b * 512 + o];
            bvs[nt][r] = seg ? conv_b[o] : 0.f;
        }
    unsigned short* yp = ypart + (size_t)seg * YSEG;
    int pcol = c0p + ln15;
    #pragma unroll
    for (int g = 0; g < 8; ++g) {
        int prow = r0 + g;
        #pragma unroll
        for (int nt = 0; nt < 2; nt++)
            #pragma unroll
            for (int r = 0; r < 4; r++) {
                int o = og * 32 + nt * 16 + kgrp * 4 + r;
                yp[((size_t)(b * 512 + o)) * NPIX + prow * HP_ + pcol] =
                    f2bf(acc[g][nt][r] * dcv[nt][r] + bvs[nt][r]);
            }
    }
}

// ---------- k_resample2: full-width 28x84 strip; LDS buffers aliased; upF bf16 ----------
// grid (3, 512, 4), 512 threads. LDS: buf1 23.76KB (yt | upF), buf2 25.34KB (upR | dv).
__global__ __launch_bounds__(512) void k_resample2(const unsigned short* __restrict__ ypart,
                                                   float* __restrict__ out, Taps taps) {
    __shared__ __align__(16) char smem[23760 + 25344];
    float (*yt)[96]           = (float(*)[96])smem;            // [38][94 used]
    unsigned short (*upF)[180] = (unsigned short(*)[180])smem; // [66][178 used]
    float (*upR)[96]          = (float(*)[96])(smem + 23760);  // [66][94 used]
    float (*dv)[180]          = (float(*)[180])(smem + 23760); // [28][178 used]

    int tid = threadIdx.x;
    int ts = blockIdx.x; int o = blockIdx.y; int b = blockIdx.z;
    int tr = ts * 28;
    const unsigned short* y0b = ypart + ((size_t)(b * 512 + o)) * NPIX;
    const unsigned short* y1b = y0b + YSEG;

    // stage 1: load y (sum of partials), rows tr-4..tr+33, cols -4..89
    for (int idx = tid; idx < 38 * 94; idx += 512) {
        int rr = idx / 94, cc = idx % 94;
        int gr = tr - 4 + rr, gc = cc - 4;
        float v = 0.f;
        if (gr >= 0 && gr < HP_ && gc >= 0 && gc < HP_) {
            int p = gr * HP_ + gc;
            v = bf2f(y0b[p]) + bf2f(y1b[p]);
        }
        yt[rr][cc] = v;
    }
    __syncthreads();
    // stage 2: vertical upsample -> upR[66][94]
    for (int idx = tid; idx < 33 * 94; idx += 512) {
        int q = idx / 94, cc = idx % 94;
        float aE = 0.f, aO = 0.f;
        #pragma unroll
        for (int u = 0; u < 6; u++) {
            float v = yt[q + u][cc];
            aE += taps.fu[2 * u + 1] * v;
            aO += taps.fu[2 * u] * v;
        }
        upR[2 * q][cc] = aE; upR[2 * q + 1][cc] = aO;
    }
    __syncthreads();
    // stage 3: horizontal upsample + act + clamp -> upF bf16 [66][178] (overwrites yt)
    for (int idx = tid; idx < 66 * 89; idx += 512) {
        int jr = idx / 89, q = idx % 89;
        float aE = 0.f, aO = 0.f;
        #pragma unroll
        for (int u = 0; u < 6; u++) {
            float v = upR[jr][q + u];
            aE += taps.fu[2 * u + 1] * v;
            aO += taps.fu[2 * u] * v;
        }
        aE = (aE < 0.f ? aE * 0.2f : aE) * 1.4142135623730951f;
        aO = (aO < 0.f ? aO * 0.2f : aO) * 1.4142135623730951f;
        aE = fminf(fmaxf(aE, -256.f), 256.f);
        aO = fminf(fmaxf(aO, -256.f), 256.f);
        unsigned int pk = (unsigned int)f2bf(aE) | ((unsigned int)f2bf(aO) << 16);
        *(unsigned int*)&upF[jr][2 * q] = pk;
    }
    __syncthreads();
    // stage 4: vertical down -> dv[28][178] (overwrites upR)
    for (int idx = tid; idx < 28 * 178; idx += 512) {
        int ii = idx / 178, jc = idx % 178;
        float a = 0.f;
        #pragma unroll
        for (int t = 0; t < 12; t++) a += taps.fd[t] * bf2f(upF[2 * ii + t][jc]);
        dv[ii][jc] = a;
    }
    __syncthreads();
    // stage 5: horizontal down + store
    for (int idx = tid; idx < 28 * 84; idx += 512) {
        int ii = idx / 84, jo = idx % 84;
        float a = 0.f;
        #pragma unroll
        for (int t = 0; t < 12; t++) a += taps.fd[t] * dv[ii][2 * jo + t];
        out[((size_t)(b * 512 + o) * 84 + (tr + ii)) * 84 + jo] = a;
    }
}

// ---------- host: Kaiser lowpass design in double ----------
static double bessel_i0(double x) {
    double s = 1.0, t = 1.0;
    for (int k = 1; k < 60; k++) {
        double u = x / (2.0 * k);
        t *= u * u;
        s += t;
        if (t < 1e-18 * s) break;
    }
    return s;
}

static void design_taps(float* h12) {
    const int N = 12;
    const double cutoff = 16.0, width = 16.0, fs = 128.0;
    double nyq = 0.5 * fs;
    double atten = 2.285 * (N - 1) * M_PI * (width / nyq) + 7.95;
    double beta;
    if (atten > 50.0) beta = 0.1102 * (atten - 8.7);
    else if (atten > 21.0) beta = 0.5842 * pow(atten - 21.0, 0.4) + 0.07886 * (atten - 21.0);
    else beta = 0.0;
    double c = cutoff / nyq;
    double h[12]; double sum = 0.0;
    double ib = bessel_i0(beta);
    for (int n = 0; n < N; n++) {
        double m = n - (N - 1) / 2.0;
        double xx = c * m;
        double sinc = (xx == 0.0) ? 1.0 : sin(M_PI * xx) / (M_PI * xx);
        double t = 2.0 * n / (N - 1) - 1.0;
        double arg = 1.0 - t * t; if (arg < 0.0) arg = 0.0;
        double w = bessel_i0(beta * sqrt(arg)) / ib;
        h[n] = c * sinc * w;
        sum += h[n];
    }
    for (int n = 0; n < N; n++) h12[n] = (float)(h[n] / sum);
}

extern "C" void kernel_launch(void* const* d_in, const int* in_sizes, int n_in,
                              void* d_out, int out_size, void* d_ws, size_t ws_size,
                              hipStream_t stream) {
    const float* x      = (const float*)d_in[0];
    const float* wlat   = (const float*)d_in[1];
    const float* aff_w  = (const float*)d_in[2];
    const float* aff_b  = (const float*)d_in[3];
    const float* conv_w = (const float*)d_in[4];
    const float* conv_b = (const float*)d_in[5];
    float* out = (float*)d_out;

    // ws layout: sn 8K | dcoef 8K | w2 1M | wn3 4.5M | xpad2 31.7M | ypart 60.6M (~98 MiB)
    char* ws = (char*)d_ws;
    float* sn    = (float*)ws;
    float* dcoef = sn + 2048;
    float* w2    = dcoef + 2048;
    unsigned short* wn3   = (unsigned short*)(w2 + 512 * 512);
    unsigned short* xpad2 = wn3 + (size_t)9 * 512 * 512;
    unsigned short* ypart = xpad2 + (size_t)B_ * 64 * XPIX * 8;
    // s_raw/parts alias ypart (consumed by k_dcoef3 before k_conv4 writes)
    float* s_raw = (float*)ypart;
    float* parts = s_raw + 2048;

    Taps taps;
    float h[12];
    design_taps(h);
    for (int t = 0; t < 12; t++) {
        taps.fu[t] = 2.0f * h[11 - t];   // (FU*UP)[::-1]
        taps.fd[t] = h[11 - t];          // FD[::-1]
    }

    k_prep   <<<dim3(1024), dim3(256), 0, stream>>>(wlat, aff_w, aff_b, conv_w, s_raw, parts, wn3, w2);
    k_dcoef3 <<<dim3(512), dim3(256), 0, stream>>>(s_raw, parts, w2, sn, dcoef);
    k_premod2<<<dim3(128, 4), dim3(256), 0, stream>>>(x, sn, xpad2);
    k_conv4  <<<dim3(2112), dim3(256), 0, stream>>>(xpad2, wn3, dcoef, conv_b, ypart);
    k_resample2<<<dim3(3, 512, 4), dim3(512), 0, stream>>>(ypart, out, taps);
}